// Round 1
// baseline (445.742 us; speedup 1.0000x reference)
//
#include <hip/hip_runtime.h>

// Gram-Schmidt orthonormalization: x (8192, 8, 1024) fp32 -> basis (8192, 8, 1024) fp32.
// One 256-thread block per batch row. Each thread holds 4 elements of each of the
// 8 vectors in registers (32 VGPRs of data). Classical GS to match reference numerics.
// Memory-bound: 256 MiB in + 256 MiB out -> target ~85-120 us.

constexpr int NE      = 8;
constexpr int DIM     = 1024;
constexpr int THREADS = 256;
constexpr int VPT     = DIM / THREADS;   // 4 elements per thread per vector
constexpr int NWAVES  = THREADS / 64;    // 4 waves

__global__ __launch_bounds__(THREADS) void gs_kernel(const float* __restrict__ x,
                                                     float* __restrict__ out) {
    const int b    = blockIdx.x;
    const int tid  = threadIdx.x;
    const int lane = tid & 63;
    const int wid  = tid >> 6;
    const size_t base = (size_t)b * NE * DIM;

    // ---- load all 8 vectors, coalesced float4 ----
    float v[NE][VPT];
    #pragma unroll
    for (int e = 0; e < NE; ++e) {
        const float4 t = *reinterpret_cast<const float4*>(x + base + (size_t)e * DIM + tid * VPT);
        v[e][0] = t.x; v[e][1] = t.y; v[e][2] = t.z; v[e][3] = t.w;
    }

    __shared__ float red[NWAVES][NE];

    // ---- normalize vector 0 ----
    {
        float s = v[0][0]*v[0][0] + v[0][1]*v[0][1] + v[0][2]*v[0][2] + v[0][3]*v[0][3];
        #pragma unroll
        for (int o = 32; o > 0; o >>= 1) s += __shfl_xor(s, o);
        if (lane == 0) red[wid][0] = s;
        __syncthreads();
        const float tot = red[0][0] + red[1][0] + red[2][0] + red[3][0];
        const float inv = 1.0f / sqrtf(tot);
        #pragma unroll
        for (int j = 0; j < VPT; ++j) v[0][j] *= inv;
        __syncthreads();   // red reused next phase
        float4 t; t.x = v[0][0]; t.y = v[0][1]; t.z = v[0][2]; t.w = v[0][3];
        *reinterpret_cast<float4*>(out + base + tid * VPT) = t;
    }

    // ---- Gram-Schmidt steps i = 1..7 (fully unrolled: all reg indices static) ----
    #pragma unroll
    for (int i = 1; i < NE; ++i) {
        // coefficients c[k] = dot(v_i, basis_k) for all k < i, one reduction phase
        #pragma unroll
        for (int k = 0; k < i; ++k) {
            float s = 0.0f;
            #pragma unroll
            for (int j = 0; j < VPT; ++j) s += v[i][j] * v[k][j];
            #pragma unroll
            for (int o = 32; o > 0; o >>= 1) s += __shfl_xor(s, o);
            if (lane == 0) red[wid][k] = s;
        }
        __syncthreads();
        float c[NE];
        #pragma unroll
        for (int k = 0; k < i; ++k)
            c[k] = red[0][k] + red[1][k] + red[2][k] + red[3][k];
        __syncthreads();   // red reused below

        // w = v_i - sum_k c[k] * basis_k   (classical GS: all c from original v_i)
        #pragma unroll
        for (int k = 0; k < i; ++k) {
            #pragma unroll
            for (int j = 0; j < VPT; ++j) v[i][j] = fmaf(-c[k], v[k][j], v[i][j]);
        }

        // normalize w
        float s = 0.0f;
        #pragma unroll
        for (int j = 0; j < VPT; ++j) s += v[i][j] * v[i][j];
        #pragma unroll
        for (int o = 32; o > 0; o >>= 1) s += __shfl_xor(s, o);
        if (lane == 0) red[wid][0] = s;
        __syncthreads();
        const float inv = 1.0f / sqrtf(red[0][0] + red[1][0] + red[2][0] + red[3][0]);
        #pragma unroll
        for (int j = 0; j < VPT; ++j) v[i][j] *= inv;
        __syncthreads();   // red reused next iteration

        float4 t; t.x = v[i][0]; t.y = v[i][1]; t.z = v[i][2]; t.w = v[i][3];
        *reinterpret_cast<float4*>(out + base + (size_t)i * DIM + tid * VPT) = t;
    }
}

extern "C" void kernel_launch(void* const* d_in, const int* in_sizes, int n_in,
                              void* d_out, int out_size, void* d_ws, size_t ws_size,
                              hipStream_t stream) {
    const float* x = (const float*)d_in[0];
    float* out = (float*)d_out;
    const int batches = in_sizes[0] / (NE * DIM);   // 8192
    gs_kernel<<<batches, THREADS, 0, stream>>>(x, out);
}

// Round 2
// 437.208 us; speedup vs baseline: 1.0195x; 1.0195x over previous
//
#include <hip/hip_runtime.h>

// Gram-Schmidt via Cholesky: basis = L^{-1} X where G = X X^T = L L^T.
// One 256-thread block per batch (8 vectors x 1024 fp32 held in registers,
// 4 floats/vector/thread). Single reduction phase (36 independent pair-dots),
// single barrier, per-thread 8x8 Cholesky, elementwise forward substitution.
// Memory-bound target: ~268 MB write + ~134-268 MB fetch -> 70-95 us.

constexpr int NE      = 8;
constexpr int DIM     = 1024;
constexpr int THREADS = 256;
constexpr int VPT     = DIM / THREADS;     // 4 elements per thread per vector
constexpr int NWAVES  = THREADS / 64;      // 4 waves
constexpr int NPAIR   = NE * (NE + 1) / 2; // 36 pair dot products

__global__ __launch_bounds__(THREADS, 4) void gs_chol_kernel(const float* __restrict__ x,
                                                             float* __restrict__ out) {
    const int b    = blockIdx.x;
    const int tid  = threadIdx.x;
    const int lane = tid & 63;
    const int wid  = tid >> 6;
    const size_t base = (size_t)b * NE * DIM;

    // ---- load all 8 vectors, coalesced float4 ----
    float v[NE][VPT];
    #pragma unroll
    for (int e = 0; e < NE; ++e) {
        const float4 t = *reinterpret_cast<const float4*>(x + base + (size_t)e * DIM + tid * VPT);
        v[e][0] = t.x; v[e][1] = t.y; v[e][2] = t.z; v[e][3] = t.w;
    }

    // ---- per-thread partials for all 36 pair dots (independent, no cross-lane) ----
    float p[NPAIR];
    #pragma unroll
    for (int i = 0; i < NE; ++i) {
        #pragma unroll
        for (int k = 0; k <= i; ++k) {
            const int d = i * (i + 1) / 2 + k;   // compile-time after unroll
            float s = v[i][0] * v[k][0];
            #pragma unroll
            for (int j = 1; j < VPT; ++j) s = fmaf(v[i][j], v[k][j], s);
            p[d] = s;
        }
    }

    // ---- single wave-reduce phase: all 36 reductions in flight together ----
    #pragma unroll
    for (int d = 0; d < NPAIR; ++d) {
        float s = p[d];
        #pragma unroll
        for (int o = 32; o > 0; o >>= 1) s += __shfl_xor(s, o);
        p[d] = s;
    }

    // ---- cross-wave combine via LDS (one barrier total) ----
    __shared__ alignas(16) float part[NPAIR][NWAVES];
    if (lane == 0) {
        #pragma unroll
        for (int d = 0; d < NPAIR; ++d) part[d][wid] = p[d];
    }
    __syncthreads();

    // ---- 8x8 Cholesky of G, redundant per thread; G rows read (broadcast) from LDS ----
    float L[NPAIR];     // lower triangle incl. diagonal, L[i*(i+1)/2 + k]
    float rinv[NE];     // 1 / L[i][i]
    #pragma unroll
    for (int i = 0; i < NE; ++i) {
        #pragma unroll
        for (int k = 0; k <= i; ++k) {
            const int d = i * (i + 1) / 2 + k;
            const float4 g4 = *reinterpret_cast<const float4*>(&part[d][0]);
            float s = (g4.x + g4.y) + (g4.z + g4.w);
            #pragma unroll
            for (int m = 0; m < k; ++m)
                s = fmaf(-L[i * (i + 1) / 2 + m], L[k * (k + 1) / 2 + m], s);
            if (k == i) {
                const float li = sqrtf(s);
                L[d]    = li;
                rinv[i] = 1.0f / li;
            } else {
                L[d] = s * rinv[k];
            }
        }
    }

    // ---- elementwise forward substitution in registers (in place), then store ----
    #pragma unroll
    for (int i = 0; i < NE; ++i) {
        #pragma unroll
        for (int j = 0; j < VPT; ++j) {
            float w = v[i][j];
            #pragma unroll
            for (int k = 0; k < i; ++k)
                w = fmaf(-L[i * (i + 1) / 2 + k], v[k][j], w);
            v[i][j] = w * rinv[i];
        }
        float4 t; t.x = v[i][0]; t.y = v[i][1]; t.z = v[i][2]; t.w = v[i][3];
        *reinterpret_cast<float4*>(out + base + (size_t)i * DIM + tid * VPT) = t;
    }
}

extern "C" void kernel_launch(void* const* d_in, const int* in_sizes, int n_in,
                              void* d_out, int out_size, void* d_ws, size_t ws_size,
                              hipStream_t stream) {
    const float* x = (const float*)d_in[0];
    float* out = (float*)d_out;
    const int batches = in_sizes[0] / (NE * DIM);   // 8192
    gs_chol_kernel<<<batches, THREADS, 0, stream>>>(x, out);
}

// Round 3
// 433.128 us; speedup vs baseline: 1.0291x; 1.0094x over previous
//
#include <hip/hip_runtime.h>

// Gram-Schmidt via Cholesky, ONE WAVE PER BATCH.
// Each 64-lane wave owns a full batch: v[8][16] fp32 in registers (128 VGPRs).
// All 36 Gram dot-products reduce wave-locally (6 shuffle levels each) -> no
// __syncthreads, no LDS, ~5x less DS-pipe traffic than the 4-wave version.
// Per-thread redundant 8x8 Cholesky, elementwise forward substitution.
// Memory-bound target: 512 MiB combined traffic -> ~90-105 us.

constexpr int NE      = 8;
constexpr int DIM     = 1024;
constexpr int THREADS = 256;
constexpr int WPB     = THREADS / 64;      // 4 independent waves (batches) per block
constexpr int EPT     = DIM / 64;          // 16 elements per thread per vector
constexpr int NPAIR   = NE * (NE + 1) / 2; // 36 pair dot products

__global__ __launch_bounds__(THREADS, 2) void gs_wave_kernel(const float* __restrict__ x,
                                                             float* __restrict__ out) {
    const int lane = threadIdx.x & 63;
    const int wid  = threadIdx.x >> 6;
    const size_t batch = (size_t)blockIdx.x * WPB + wid;
    const float* xb = x   + batch * NE * DIM + lane * 4;
    float*       ob = out + batch * NE * DIM + lane * 4;

    // ---- load: per instruction the wave covers a contiguous 1 KiB (coalesced) ----
    // element mapping: v[e][q*4+j] = x[batch, e, q*256 + lane*4 + j]
    float v[NE][EPT];
    #pragma unroll
    for (int e = 0; e < NE; ++e) {
        #pragma unroll
        for (int q = 0; q < 4; ++q) {
            const float4 t = *reinterpret_cast<const float4*>(xb + e * DIM + q * 256);
            v[e][q * 4 + 0] = t.x; v[e][q * 4 + 1] = t.y;
            v[e][q * 4 + 2] = t.z; v[e][q * 4 + 3] = t.w;
        }
    }

    // ---- per-thread partials for all 36 pair dots ----
    float p[NPAIR];
    #pragma unroll
    for (int i = 0; i < NE; ++i) {
        #pragma unroll
        for (int k = 0; k <= i; ++k) {
            float s = 0.0f;
            #pragma unroll
            for (int j = 0; j < EPT; ++j) s = fmaf(v[i][j], v[k][j], s);
            p[i * (i + 1) / 2 + k] = s;
        }
    }

    // ---- wave-local butterfly reduce (all lanes end with totals; no LDS) ----
    #pragma unroll
    for (int d = 0; d < NPAIR; ++d) {
        float s = p[d];
        #pragma unroll
        for (int o = 32; o > 0; o >>= 1) s += __shfl_xor(s, o);
        p[d] = s;
    }

    // ---- 8x8 Cholesky of G, redundant per thread (registers only) ----
    float L[NPAIR];
    float rinv[NE];
    #pragma unroll
    for (int i = 0; i < NE; ++i) {
        #pragma unroll
        for (int k = 0; k <= i; ++k) {
            float s = p[i * (i + 1) / 2 + k];
            #pragma unroll
            for (int m = 0; m < k; ++m)
                s = fmaf(-L[i * (i + 1) / 2 + m], L[k * (k + 1) / 2 + m], s);
            if (k == i) {
                const float li = sqrtf(s);
                L[i * (i + 1) / 2 + i] = li;
                rinv[i] = 1.0f / li;
            } else {
                L[i * (i + 1) / 2 + k] = s * rinv[k];
            }
        }
    }

    // ---- elementwise forward substitution in registers, streamed stores ----
    #pragma unroll
    for (int i = 0; i < NE; ++i) {
        #pragma unroll
        for (int j = 0; j < EPT; ++j) {
            float w = v[i][j];
            #pragma unroll
            for (int k = 0; k < i; ++k)
                w = fmaf(-L[i * (i + 1) / 2 + k], v[k][j], w);
            v[i][j] = w * rinv[i];
        }
        #pragma unroll
        for (int q = 0; q < 4; ++q) {
            float4 t;
            t.x = v[i][q * 4 + 0]; t.y = v[i][q * 4 + 1];
            t.z = v[i][q * 4 + 2]; t.w = v[i][q * 4 + 3];
            *reinterpret_cast<float4*>(ob + i * DIM + q * 256) = t;
        }
    }
}

extern "C" void kernel_launch(void* const* d_in, const int* in_sizes, int n_in,
                              void* d_out, int out_size, void* d_ws, size_t ws_size,
                              hipStream_t stream) {
    const float* x = (const float*)d_in[0];
    float* out = (float*)d_out;
    const int batches = in_sizes[0] / (NE * DIM);   // 8192
    gs_wave_kernel<<<batches / WPB, THREADS, 0, stream>>>(x, out);
}